// Round 9
// baseline (84.264 us; speedup 1.0000x reference)
//
#include <hip/hip_runtime.h>
#include <math.h>

// Problem constants
#define BB   64
#define LL   4096
#define DKC  128
#define DVC  128
#define HC   4
#define DKLC 64
#define DVLC 128
#define RC   128

#define NCA  64            // 64-row slots per batch (partial granularity)
#define NCH  4             // 16-row chunks per slot (per wave)
#define WPB  4             // waves per block

// Nontemporal float4 load (bypass cache allocation for streamed-once data)
typedef float f4v __attribute__((ext_vector_type(4)));
__device__ __forceinline__ float4 ntload4(const float4* p) {
    f4v v = __builtin_nontemporal_load((const f4v*)p);
    return make_float4(v.x, v.y, v.z, v.w);
}
__device__ __forceinline__ float dot4(float4 a, float4 b) {
    return a.x * b.x + a.y * b.y + a.z * b.z + a.w * b.w;
}

// ---------------------------------------------------------------------------
// Kernel 0: fold q[h][d] = sum_k Wq[h,k] * Wk[d,h,k]   (H*DK = 512 values)
// ---------------------------------------------------------------------------
__global__ __launch_bounds__(512) void k_foldq(const float* __restrict__ Wq,
                                               const float* __restrict__ Wk,
                                               float* __restrict__ q) {
    int t = threadIdx.x;            // 0..511
    int h = t >> 7;                 // 0..3
    int d = t & 127;                // 0..127
    float acc = 0.f;
#pragma unroll 8
    for (int k = 0; k < DKLC; ++k)
        acc += Wq[h * DKLC + k] * Wk[(d * HC + h) * DKLC + k];
    q[h * DKC + d] = acc;
}

// ---------------------------------------------------------------------------
// Wave-independent, software-pipelined fused kernel.
// Wave W owns 64 contiguous rows (slot ws of batch b), processed as NCH=4
// chunks of 16 rows with online-softmax accumulation. Explicit register
// double-buffer (kA/kB, vA/vB) + staggered prefetch keeps next-chunk loads
// in flight under current-chunk compute. NO LDS, NO __syncthreads -> no
// vmcnt(0) drain ever interrupts the prefetch pipeline.
// ---------------------------------------------------------------------------
struct KBuf { float4 k0[4], k1[4]; int mk[4]; };
struct VBuf { float4 vv[8]; };

__global__ __launch_bounds__(256, 2) void k_fused(const float* __restrict__ K,
                                                  const float* __restrict__ V,
                                                  const int*   __restrict__ mask,
                                                  const float* __restrict__ q,
                                                  float* __restrict__ stats,
                                                  float* __restrict__ partWV) {
    const int t   = threadIdx.x;
    const int w   = t >> 6;
    const int ln  = t & 63;
    const int W   = blockIdx.x * WPB + w;   // global wave id
    const int b   = W >> 6;                 // batch
    const int ws  = W & 63;                 // 64-row slot within batch
    const int lin = ln & 15;                // lane-in-row (score stage)
    const int rh  = ln >> 5;                // row-half (PV stage)

    const float4* Kb    = (const float4*)(K + (long)b * LL * DKC);
    const float4* Vb    = (const float4*)(V + (long)b * LL * DVC);
    const int*    maskb = mask + (long)b * LL;

    // folded q fragments (cached, broadcast)
    float4 qa[HC], qb[HC];
#pragma unroll
    for (int h = 0; h < HC; ++h) {
        qa[h] = ((const float4*)q)[h * 32 + lin];
        qb[h] = ((const float4*)q)[h * 32 + 16 + lin];
    }

    const float scale = 0.08838834764831844f;   // 1/sqrt(128)
    float4 m_run = make_float4(-INFINITY, -INFINITY, -INFINITY, -INFINITY);
    float4 Z_run = make_float4(0.f, 0.f, 0.f, 0.f);
    float4 acc[HC];
#pragma unroll
    for (int h = 0; h < HC; ++h) acc[h] = make_float4(0.f, 0.f, 0.f, 0.f);
    float4 pp[4];

    KBuf kA, kB;
    VBuf vA, vB;

    // issue chunk-j K loads (4x2 NT float4 + 4 mask ints per wave)
    auto LK = [&](KBuf& Bf, int j) {
        int rb = ws * 64 + j * 16;
#pragma unroll
        for (int p = 0; p < 4; ++p) {
            int rp = rb + p * 4 + (ln >> 4);
            Bf.k0[p] = ntload4(&Kb[rp * 32 + lin]);        // 4 rows x 256 B
            Bf.k1[p] = ntload4(&Kb[rp * 32 + 16 + lin]);
            Bf.mk[p] = __builtin_nontemporal_load(maskb + rp);
        }
    };
    // issue chunk-j V loads (8 NT float4 per wave)
    auto LV = [&](VBuf& Bf, int j) {
        int rb = ws * 64 + j * 16;
#pragma unroll
        for (int it = 0; it < 8; ++it)
            Bf.vv[it] = ntload4(&Vb[(rb + it * 2 + rh) * 32 + (ln & 31)]);
    };
    // scores + online-softmax update (rescales acc/Z to new running max)
    auto SCORE = [&](const KBuf& Bf) {
        float4 d[4];
#pragma unroll
        for (int p = 0; p < 4; ++p) {
            float4 dd;
            dd.x = dot4(Bf.k0[p], qa[0]) + dot4(Bf.k1[p], qb[0]);
            dd.y = dot4(Bf.k0[p], qa[1]) + dot4(Bf.k1[p], qb[1]);
            dd.z = dot4(Bf.k0[p], qa[2]) + dot4(Bf.k1[p], qb[2]);
            dd.w = dot4(Bf.k0[p], qa[3]) + dot4(Bf.k1[p], qb[3]);
#pragma unroll
            for (int off = 1; off <= 8; off <<= 1) {
                dd.x += __shfl_xor(dd.x, off);
                dd.y += __shfl_xor(dd.y, off);
                dd.z += __shfl_xor(dd.z, off);
                dd.w += __shfl_xor(dd.w, off);
            }
            d[p].x = Bf.mk[p] ? -INFINITY : dd.x * scale;
            d[p].y = Bf.mk[p] ? -INFINITY : dd.y * scale;
            d[p].z = Bf.mk[p] ? -INFINITY : dd.z * scale;
            d[p].w = Bf.mk[p] ? -INFINITY : dd.w * scale;
        }
        float4 mc;
        mc.x = fmaxf(fmaxf(d[0].x, d[1].x), fmaxf(d[2].x, d[3].x));
        mc.y = fmaxf(fmaxf(d[0].y, d[1].y), fmaxf(d[2].y, d[3].y));
        mc.z = fmaxf(fmaxf(d[0].z, d[1].z), fmaxf(d[2].z, d[3].z));
        mc.w = fmaxf(fmaxf(d[0].w, d[1].w), fmaxf(d[2].w, d[3].w));
#pragma unroll
        for (int off = 16; off <= 32; off <<= 1) {
            mc.x = fmaxf(mc.x, __shfl_xor(mc.x, off));
            mc.y = fmaxf(mc.y, __shfl_xor(mc.y, off));
            mc.z = fmaxf(mc.z, __shfl_xor(mc.z, off));
            mc.w = fmaxf(mc.w, __shfl_xor(mc.w, off));
        }
        float4 mnew;
        mnew.x = fmaxf(m_run.x, mc.x);
        mnew.y = fmaxf(m_run.y, mc.y);
        mnew.z = fmaxf(m_run.z, mc.z);
        mnew.w = fmaxf(m_run.w, mc.w);
        float4 mu;                              // all-masked guard
        mu.x = (mnew.x == -INFINITY) ? 0.f : mnew.x;
        mu.y = (mnew.y == -INFINITY) ? 0.f : mnew.y;
        mu.z = (mnew.z == -INFINITY) ? 0.f : mnew.z;
        mu.w = (mnew.w == -INFINITY) ? 0.f : mnew.w;
        float4 f;                               // expf(-inf)=0: exact
        f.x = expf(m_run.x - mu.x);
        f.y = expf(m_run.y - mu.y);
        f.z = expf(m_run.z - mu.z);
        f.w = expf(m_run.w - mu.w);
        acc[0].x *= f.x; acc[0].y *= f.x; acc[0].z *= f.x; acc[0].w *= f.x;
        acc[1].x *= f.y; acc[1].y *= f.y; acc[1].z *= f.y; acc[1].w *= f.y;
        acc[2].x *= f.z; acc[2].y *= f.z; acc[2].z *= f.z; acc[2].w *= f.z;
        acc[3].x *= f.w; acc[3].y *= f.w; acc[3].z *= f.w; acc[3].w *= f.w;
#pragma unroll
        for (int p = 0; p < 4; ++p) {
            pp[p].x = expf(d[p].x - mu.x);
            pp[p].y = expf(d[p].y - mu.y);
            pp[p].z = expf(d[p].z - mu.z);
            pp[p].w = expf(d[p].w - mu.w);
        }
        float4 z;
        z.x = pp[0].x + pp[1].x + pp[2].x + pp[3].x;
        z.y = pp[0].y + pp[1].y + pp[2].y + pp[3].y;
        z.z = pp[0].z + pp[1].z + pp[2].z + pp[3].z;
        z.w = pp[0].w + pp[1].w + pp[2].w + pp[3].w;
#pragma unroll
        for (int off = 16; off <= 32; off <<= 1) {
            z.x += __shfl_xor(z.x, off);
            z.y += __shfl_xor(z.y, off);
            z.z += __shfl_xor(z.z, off);
            z.w += __shfl_xor(z.w, off);
        }
        Z_run.x = Z_run.x * f.x + z.x;
        Z_run.y = Z_run.y * f.y + z.y;
        Z_run.z = Z_run.z * f.z + z.z;
        Z_run.w = Z_run.w * f.w + z.w;
        m_run = mnew;
    };
    // PV accumulate: P routed to (row-half, col) layout via static shfl
    auto PV = [&](const VBuf& Bf) {
#pragma unroll
        for (int it = 0; it < 8; ++it) {
            int src = (((2 * it) & 3) + rh) * 16 + lin;
            float4 w4;
            w4.x = __shfl(pp[it >> 1].x, src);
            w4.y = __shfl(pp[it >> 1].y, src);
            w4.z = __shfl(pp[it >> 1].z, src);
            w4.w = __shfl(pp[it >> 1].w, src);
            float4 v = Bf.vv[it];
            acc[0].x += w4.x*v.x; acc[0].y += w4.x*v.y; acc[0].z += w4.x*v.z; acc[0].w += w4.x*v.w;
            acc[1].x += w4.y*v.x; acc[1].y += w4.y*v.y; acc[1].z += w4.y*v.z; acc[1].w += w4.y*v.w;
            acc[2].x += w4.z*v.x; acc[2].y += w4.z*v.y; acc[2].z += w4.z*v.z; acc[2].w += w4.z*v.w;
            acc[3].x += w4.w*v.x; acc[3].y += w4.w*v.y; acc[3].z += w4.w*v.z; acc[3].w += w4.w*v.w;
        }
    };

    // ---- software-pipelined chunk schedule (NCH = 4, fully static) ----
    LK(kA, 0); LV(vA, 0);
    LK(kB, 1); SCORE(kA); LV(vB, 1); PV(vA);
    LK(kA, 2); SCORE(kB); LV(vA, 2); PV(vB);
    LK(kB, 3); SCORE(kA); LV(vB, 3); PV(vA);
    SCORE(kB); PV(vB);

    // ---- final: pair-combine row halves, write wave partial ----
#pragma unroll
    for (int h = 0; h < HC; ++h) {
        acc[h].x += __shfl_xor(acc[h].x, 32);
        acc[h].y += __shfl_xor(acc[h].y, 32);
        acc[h].z += __shfl_xor(acc[h].z, 32);
        acc[h].w += __shfl_xor(acc[h].w, 32);
    }
    const long slot = (long)b * NCA + ws;
    if (ln == 0) {
        stats[slot * 8 + 0] = m_run.x;
        stats[slot * 8 + 1] = m_run.y;
        stats[slot * 8 + 2] = m_run.z;
        stats[slot * 8 + 3] = m_run.w;
        stats[slot * 8 + 4] = Z_run.x;
        stats[slot * 8 + 5] = Z_run.y;
        stats[slot * 8 + 6] = Z_run.z;
        stats[slot * 8 + 7] = Z_run.w;
    }
    if (ln < 32) {
#pragma unroll
        for (int h = 0; h < HC; ++h)
            ((float4*)partWV)[(slot * HC + h) * (DVC / 4) + ln] = acc[h];
    }
}

// ---------------------------------------------------------------------------
// Epilogue: combine 64 slot-partials per b (wave = head, lane = slot),
// then QKV = (1/L) WV*Wv ; out = QKV*Wo.   One block per b.
// ---------------------------------------------------------------------------
__global__ __launch_bounds__(256) void k_out(const float* __restrict__ stats,
                                             const float* __restrict__ partWV,
                                             const float* __restrict__ Wv,
                                             const float* __restrict__ Wo,
                                             float* __restrict__ out) {
    int b = blockIdx.x;
    int t = threadIdx.x;
    __shared__ float WV[HC][DVC];        // 2 KB
    __shared__ float QKV[HC * DVLC];     // 2 KB
    __shared__ float sc[NCA][HC];        // 1 KB rescale factors
    __shared__ float zinv[HC];

    // wave h2 = head, lane a = slot (NCA = 64 = wave width)
    {
        int h2 = t >> 6, a = t & 63;
        float ma = stats[((long)b * NCA + a) * 8 + h2];
        float za = stats[((long)b * NCA + a) * 8 + 4 + h2];
        float m = ma;
#pragma unroll
        for (int off = 32; off; off >>= 1) m = fmaxf(m, __shfl_xor(m, off));
        // l=0 is never masked -> m finite, Z > 0
        float f  = (ma == -INFINITY) ? 0.f : expf(ma - m);
        sc[a][h2] = f;
        float fz = f * za;
#pragma unroll
        for (int off = 32; off; off >>= 1) fz += __shfl_xor(fz, off);
        if (a == 0) zinv[h2] = 1.0f / fz;
    }
    __syncthreads();

    for (int j = t; j < HC * DVC; j += 256) {
        int h = j >> 7, e = j & 127;
        float acc = 0.f;
#pragma unroll 8
        for (int p = 0; p < NCA; ++p)
            acc += sc[p][h] * partWV[(((long)b * NCA + p) * HC + h) * DVC + e];
        WV[h][e] = acc * zinv[h];
    }
    __syncthreads();

    for (int j = t; j < HC * DVLC; j += 256) {
        int h = j >> 7, vv = j & 127;
        float acc = 0.f;
#pragma unroll 8
        for (int e = 0; e < DVC; ++e)
            acc += WV[h][e] * Wv[(e * HC + h) * DVLC + vv];
        QKV[j] = acc * (1.0f / LL);
    }
    __syncthreads();

    for (int r = t; r < RC; r += 256) {
        float acc = 0.f;
#pragma unroll 8
        for (int i = 0; i < HC * DVLC; ++i)
            acc += QKV[i] * Wo[i * RC + r];
        out[b * RC + r] = acc;
    }
}

// ---------------------------------------------------------------------------
extern "C" void kernel_launch(void* const* d_in, const int* in_sizes, int n_in,
                              void* d_out, int out_size, void* d_ws, size_t ws_size,
                              hipStream_t stream) {
    (void)in_sizes; (void)n_in; (void)out_size; (void)ws_size;
    const float* K    = (const float*)d_in[0];
    const float* V    = (const float*)d_in[1];
    const int*   mask = (const int*)  d_in[2];
    const float* Wq   = (const float*)d_in[3];
    const float* Wk   = (const float*)d_in[4];
    const float* Wv   = (const float*)d_in[5];
    const float* Wo   = (const float*)d_in[6];
    float* out = (float*)d_out;

    float* q      = (float*)d_ws;                         // 512
    float* stats  = q + 512;                              // B*NCA*8   = 32768
    float* partWV = stats + (long)BB * NCA * 8;           // B*NCA*H*DV = 2M floats

    k_foldq<<<1, 512, 0, stream>>>(Wq, Wk, q);
    k_fused<<<BB * NCA / WPB, 256, 0, stream>>>(K, V, mask, q, stats, partWV);
    k_out<<<BB, 256, 0, stream>>>(stats, partWV, Wv, Wo, out);
}